// Round 1
// baseline (182.093 us; speedup 1.0000x reference)
//
#include <hip/hip_runtime.h>

#define B 8
#define N 4096
#define NITER 4
#define SPLIT 32
#define CHUNK (N / SPLIT)   // 128 rows of P per partial block

// Partial product over a chunk of the b (inner) dimension.
// partial[chunk][i][a] = prod_{b in chunk} (1 - P[b,a] * pred[i,b])
__global__ __launch_bounds__(256) void partial_kernel(const float* __restrict__ pred,
                                                      const float* __restrict__ P,
                                                      float* __restrict__ partial) {
    const int a = blockIdx.x * 256 + threadIdx.x;   // output column, coalesced
    const int chunk = blockIdx.y;
    const int b0 = chunk * CHUNK;

    float prod[B];
#pragma unroll
    for (int i = 0; i < B; ++i) prod[i] = 1.0f;

    const float* Pp = P + (size_t)b0 * N + a;
    const float* predp = pred + b0;

#pragma unroll 4
    for (int b = 0; b < CHUNK; ++b) {
        const float p = Pp[(size_t)b * N];          // coalesced across lanes
#pragma unroll
        for (int i = 0; i < B; ++i) {
            const float pr = predp[i * N + b];      // wave-uniform, broadcast
            prod[i] *= fmaf(-p, pr, 1.0f);
        }
    }

#pragma unroll
    for (int i = 0; i < B; ++i)
        partial[((size_t)chunk * B + i) * N + a] = prod[i];
}

// out[i,a] = seed ? 1 : 1 - prod_s partial[s][i][a]
__global__ __launch_bounds__(256) void reduce_kernel(const float* __restrict__ partial,
                                                     const float* __restrict__ mask,
                                                     float* __restrict__ out) {
    const int idx = blockIdx.x * 256 + threadIdx.x;   // idx = i*N + a
    float prod = 1.0f;
#pragma unroll
    for (int s = 0; s < SPLIT; ++s)
        prod *= partial[(size_t)s * (B * N) + idx];
    const float v = 1.0f - prod;
    out[idx] = (mask[idx] != 0.0f) ? 1.0f : v;
}

__global__ void seed_mask_kernel(const int* __restrict__ seed_idx, float* __restrict__ mask,
                                 int nseeds) {
    const int k = blockIdx.x * blockDim.x + threadIdx.x;
    if (k < nseeds) {
        const int b = seed_idx[2 * k + 0];
        const int n = seed_idx[2 * k + 1];
        mask[b * N + n] = 1.0f;
    }
}

extern "C" void kernel_launch(void* const* d_in, const int* in_sizes, int n_in,
                              void* d_out, int out_size, void* d_ws, size_t ws_size,
                              hipStream_t stream) {
    const float* preds    = (const float*)d_in[0];   // [B, N]
    const float* P        = (const float*)d_in[1];   // [N, N]
    const int*   seed_idx = (const int*)d_in[2];     // [NSEEDS, 2]
    const int nseeds = in_sizes[2] / 2;

    float* out = (float*)d_out;                      // [B, N]
    float* partial = (float*)d_ws;                           // SPLIT*B*N floats = 4 MiB
    float* mask    = partial + (size_t)SPLIT * B * N;        // B*N floats = 128 KiB

    // Build seed mask (ws is re-poisoned before every launch, so rebuild every call).
    hipMemsetAsync(mask, 0, (size_t)B * N * sizeof(float), stream);
    seed_mask_kernel<<<1, 128, 0, stream>>>(seed_idx, mask, nseeds);

    for (int it = 0; it < NITER; ++it) {
        const float* cur = (it == 0) ? preds : out;
        partial_kernel<<<dim3(N / 256, SPLIT), 256, 0, stream>>>(cur, P, partial);
        reduce_kernel<<<dim3((B * N) / 256), 256, 0, stream>>>(partial, mask, out);
    }
}